// Round 6
// baseline (287.858 us; speedup 1.0000x reference)
//
#include <hip/hip_runtime.h>
#include <math.h>
#include <float.h>

#define NN 8192

typedef __bf16 bf16x8 __attribute__((ext_vector_type(8)));
typedef float f32x4 __attribute__((ext_vector_type(4)));

constexpr float POS_R2 = 0.0375f * 0.0375f;
constexpr float NEG_R2 = 0.1f * 0.1f;
constexpr float EPSF = 1e-7f;
constexpr float PRC = POS_R2 - EPSF;  // pos:  d2p < PRC
constexpr float NRC = NEG_R2 - EPSF;  // neg:  d2p > NRC
constexpr float POS_TH = 0.1f;
constexpr float NEG_TH = 1.4f;

// ws byte offsets
#define FT_OFF 0                          // bf16 [NN][32] tgt feats
#define FS2_OFF (NN * 64)                 // bf16 [NN][32] -2 * src feats
#define PSX_OFF (2 * NN * 64)             // bf16 [NN][32] src pos ext (A side)
#define PTX_OFF (3 * NN * 64)             // bf16 [NN][32] tgt pos ext (B side)
#define FNS_OFF (4 * NN * 64)             // f32 [NN] src feat |.|^2 (rounded feats)
#define FNT_OFF (4 * NN * 64 + NN * 4)    // f32 [NN] tgt feat |.|^2
#define MAXB_OFF (4 * NN * 64 + 2 * NN * 4)
#define MINB_OFF (4 * NN * 64 + 3 * NN * 4)

// ---------------------------------------------------------------------------
// Phase 1: gather + transform + bf16 conversion + MFMA operand packing.
// 4 threads per correspondence: part p handles feat dims [8p, 8p+8);
// p==1 builds src position-ext row, p==2 builds tgt position-ext row.
// ---------------------------------------------------------------------------
__global__ __launch_bounds__(256) void hcl_prep(
    const float* __restrict__ src_pcd, const float* __restrict__ tgt_pcd,
    const float* __restrict__ src_feats, const float* __restrict__ tgt_feats,
    const int* __restrict__ corr, const float* __restrict__ rot,
    const float* __restrict__ trans, char* __restrict__ ws) {
  int t = blockIdx.x * 256 + threadIdx.x;  // 0..32767
  int i = t >> 2;
  int p = t & 3;
  int ci = corr[2 * i];
  int cj = corr[2 * i + 1];

  // ---- feats: this part's 8 dims = float4 chunks 2p, 2p+1 ----
  const float4* sf = (const float4*)(src_feats + (size_t)ci * 32);
  const float4* tf = (const float4*)(tgt_feats + (size_t)cj * 32);
  float na = 0.f, nb = 0.f;
  bf16x8 osrc, otgt;
#pragma unroll
  for (int h = 0; h < 2; ++h) {
    float4 a = sf[2 * p + h];
    __bf16 h0 = (__bf16)a.x, h1 = (__bf16)a.y, h2 = (__bf16)a.z, h3 = (__bf16)a.w;
    float f0 = (float)h0, f1 = (float)h1, f2 = (float)h2, f3 = (float)h3;
    na += f0 * f0 + f1 * f1 + f2 * f2 + f3 * f3;
    osrc[4 * h + 0] = (__bf16)(-2.f * f0);
    osrc[4 * h + 1] = (__bf16)(-2.f * f1);
    osrc[4 * h + 2] = (__bf16)(-2.f * f2);
    osrc[4 * h + 3] = (__bf16)(-2.f * f3);

    float4 b = tf[2 * p + h];
    __bf16 g0 = (__bf16)b.x, g1 = (__bf16)b.y, g2 = (__bf16)b.z, g3 = (__bf16)b.w;
    nb += (float)g0 * (float)g0 + (float)g1 * (float)g1 + (float)g2 * (float)g2 +
          (float)g3 * (float)g3;
    otgt[4 * h + 0] = g0;
    otgt[4 * h + 1] = g1;
    otgt[4 * h + 2] = g2;
    otgt[4 * h + 3] = g3;
  }
  *(bf16x8*)(ws + FS2_OFF + (size_t)i * 64 + p * 16) = osrc;
  *(bf16x8*)(ws + FT_OFF + (size_t)i * 64 + p * 16) = otgt;

  // reduce norms across the 4 parts (adjacent lanes)
  na += __shfl_xor(na, 1, 4);
  na += __shfl_xor(na, 2, 4);
  nb += __shfl_xor(nb, 1, 4);
  nb += __shfl_xor(nb, 2, 4);

  __bf16 one = (__bf16)1.0f, zero = (__bf16)0.0f;

  if (p == 0) {
    ((float*)(ws + FNS_OFF))[i] = na;
    ((float*)(ws + FNT_OFF))[i] = nb;
    ((unsigned int*)(ws + MAXB_OFF))[i] = 0u;           // max(d2f) sentinel
    ((unsigned int*)(ws + MINB_OFF))[i] = 0x7F7FFFFFu;  // FLT_MAX bits
  } else if (p == 1) {
    // src position-ext row: [ahi(3), ahi(3), alo(3), sahi, salo, 1, 1, 0...]
    float r00 = rot[0], r01 = rot[1], r02 = rot[2];
    float r10 = rot[3], r11 = rot[4], r12 = rot[5];
    float r20 = rot[6], r21 = rot[7], r22 = rot[8];
    float t0 = trans[0], t1 = trans[1], t2 = trans[2];
    float px = src_pcd[ci * 3 + 0], py = src_pcd[ci * 3 + 1], pz = src_pcd[ci * 3 + 2];
    float qx = r00 * px + r01 * py + r02 * pz + t0;
    float qy = r10 * px + r11 * py + r12 * pz + t1;
    float qz = r20 * px + r21 * py + r22 * pz + t2;
    float sa = qx * qx + qy * qy + qz * qz;
    __bf16 qhx = (__bf16)qx, qhy = (__bf16)qy, qhz = (__bf16)qz;
    __bf16 qlx = (__bf16)(qx - (float)qhx);
    __bf16 qly = (__bf16)(qy - (float)qhy);
    __bf16 qlz = (__bf16)(qz - (float)qhz);
    __bf16 sah = (__bf16)sa;
    __bf16 sal = (__bf16)(sa - (float)sah);
    bf16x8 v0, v1, vz;
    v0[0] = qhx; v0[1] = qhy; v0[2] = qhz; v0[3] = qhx; v0[4] = qhy; v0[5] = qhz;
    v0[6] = qlx; v0[7] = qly;
    v1[0] = qlz; v1[1] = sah; v1[2] = sal; v1[3] = one; v1[4] = one;
    v1[5] = zero; v1[6] = zero; v1[7] = zero;
#pragma unroll
    for (int k = 0; k < 8; ++k) vz[k] = zero;
    bf16x8* o = (bf16x8*)(ws + PSX_OFF + (size_t)i * 64);
    o[0] = v0; o[1] = v1; o[2] = vz; o[3] = vz;
  } else if (p == 2) {
    // tgt position-ext row: [-2bhi(3), -2blo(3), -2bhi(3), 1, 1, sbhi, sblo, 0...]
    float ux = tgt_pcd[cj * 3 + 0], uy = tgt_pcd[cj * 3 + 1], uz = tgt_pcd[cj * 3 + 2];
    float sb = ux * ux + uy * uy + uz * uz;
    __bf16 uhx = (__bf16)ux, uhy = (__bf16)uy, uhz = (__bf16)uz;
    __bf16 ulx = (__bf16)(ux - (float)uhx);
    __bf16 uly = (__bf16)(uy - (float)uhy);
    __bf16 ulz = (__bf16)(uz - (float)uhz);
    __bf16 sbh = (__bf16)sb;
    __bf16 sbl = (__bf16)(sb - (float)sbh);
    __bf16 m2hx = (__bf16)(-2.f * (float)uhx), m2hy = (__bf16)(-2.f * (float)uhy),
           m2hz = (__bf16)(-2.f * (float)uhz);
    __bf16 m2lx = (__bf16)(-2.f * (float)ulx), m2ly = (__bf16)(-2.f * (float)uly),
           m2lz = (__bf16)(-2.f * (float)ulz);
    bf16x8 w0, w1, wz;
    w0[0] = m2hx; w0[1] = m2hy; w0[2] = m2hz; w0[3] = m2lx; w0[4] = m2ly; w0[5] = m2lz;
    w0[6] = m2hx; w0[7] = m2hy;
    w1[0] = m2hz; w1[1] = one; w1[2] = one; w1[3] = sbh; w1[4] = sbl;
    w1[5] = zero; w1[6] = zero; w1[7] = zero;
#pragma unroll
    for (int k = 0; k < 8; ++k) wz[k] = zero;
    bf16x8* o = (bf16x8*)(ws + PTX_OFF + (size_t)i * 64);
    o[0] = w0; o[1] = w1; o[2] = wz; o[3] = wz;
  }
}

// ---------------------------------------------------------------------------
// Phase 2: MFMA pairwise distances + masked row max/min. No LDS, no barriers.
// Wave = 32 rows (two 16x16 tiles) x 256 cols, FULLY UNROLLED: 16 col-groups
// as one static straight-line body. No dynamic back-edge -> the scheduler can
// hoist loads many groups deep (bounded only by the 128-VGPR budget), turning
// the previous per-iteration {load -> vmcnt-stall -> compute} chain into a
// pipelined stream. Every prior variant (R0/R1/R3/R4/R5) had a dynamic outer
// loop and all landed 40-56us with no pipe >35% busy -- latency-serialized.
// Grid = (32 j-chunks of 256, 64 row-blocks) = 2048 blocks (R3 geometry, best
// measured). bpos/apos for quads 2/3 structurally zero -> skip those loads.
// launch_bounds(256,4): VGPR cap 128. (256,8) clamps to 32 and spills: never.
// ---------------------------------------------------------------------------
__global__ __launch_bounds__(256, 4) void hcl_dist(char* __restrict__ ws) {
  const int lane = threadIdx.x & 63;
  const int wave = threadIdx.x >> 6;
  const int quad = lane >> 4;
  const int n = lane & 15;
  const int i0 = blockIdx.y * 128 + wave * 32;
  const int j0 = blockIdx.x * 256;
  const size_t aoff = (size_t)quad * 16;
  const bool ldp = quad < 2;  // pos-ext K=16..31 is structurally zero

  // A-side fragments (constant over the j loop)
  const bf16x8 afeat0 = *(const bf16x8*)(ws + FS2_OFF + (size_t)(i0 + n) * 64 + aoff);
  const bf16x8 afeat1 = *(const bf16x8*)(ws + FS2_OFF + (size_t)(i0 + 16 + n) * 64 + aoff);
  bf16x8 apos0, apos1;
  if (ldp) {
    apos0 = *(const bf16x8*)(ws + PSX_OFF + (size_t)(i0 + n) * 64 + aoff);
    apos1 = *(const bf16x8*)(ws + PSX_OFF + (size_t)(i0 + 16 + n) * 64 + aoff);
  } else {
#pragma unroll
    for (int k = 0; k < 8; ++k) { apos0[k] = (__bf16)0.0f; apos1[k] = (__bf16)0.0f; }
  }
  const f32x4 fa0 = *(const f32x4*)(ws + FNS_OFF + (size_t)(i0 + quad * 4) * 4);
  const f32x4 fa1 = *(const f32x4*)(ws + FNS_OFF + (size_t)(i0 + 16 + quad * 4) * 4);

  float maxv[8], minv[8];
#pragma unroll
  for (int r = 0; r < 8; ++r) {
    maxv[r] = -1.0f;
    minv[r] = FLT_MAX;
  }

  const char* pF = ws + FT_OFF + (size_t)(j0 + n) * 64 + aoff;
  const char* pP = ws + PTX_OFF + (size_t)(j0 + n) * 64 + aoff;
  const char* pN = ws + FNT_OFF + (size_t)(j0 + n) * 4;

#pragma unroll
  for (int g = 0; g < 16; ++g) {
    const bf16x8 bfeat = *(const bf16x8*)(pF + g * 1024);
    bf16x8 bpos;
#pragma unroll
    for (int k = 0; k < 8; ++k) bpos[k] = (__bf16)0.0f;
    if (ldp) bpos = *(const bf16x8*)(pP + g * 1024);
    const float fb = *(const float*)(pN + g * 64);

    f32x4 c0, c1, z;
    c0[0] = fa0[0] + fb; c0[1] = fa0[1] + fb; c0[2] = fa0[2] + fb; c0[3] = fa0[3] + fb;
    c1[0] = fa1[0] + fb; c1[1] = fa1[1] + fb; c1[2] = fa1[2] + fb; c1[3] = fa1[3] + fb;
    z[0] = 0.f; z[1] = 0.f; z[2] = 0.f; z[3] = 0.f;

    f32x4 d0 = __builtin_amdgcn_mfma_f32_16x16x32_bf16(afeat0, bfeat, c0, 0, 0, 0);
    f32x4 d1 = __builtin_amdgcn_mfma_f32_16x16x32_bf16(afeat1, bfeat, c1, 0, 0, 0);
    f32x4 u0 = __builtin_amdgcn_mfma_f32_16x16x32_bf16(apos0, bpos, z, 0, 0, 0);
    f32x4 u1 = __builtin_amdgcn_mfma_f32_16x16x32_bf16(apos1, bpos, z, 0, 0, 0);

#pragma unroll
    for (int r = 0; r < 4; ++r) {
      bool p0 = u0[r] < PRC, g0 = u0[r] > NRC;
      maxv[r] = fmaxf(maxv[r], p0 ? d0[r] : -1.0f);
      minv[r] = fminf(minv[r], g0 ? d0[r] : FLT_MAX);
      bool p1 = u1[r] < PRC, g1 = u1[r] > NRC;
      maxv[4 + r] = fmaxf(maxv[4 + r], p1 ? d1[r] : -1.0f);
      minv[4 + r] = fminf(minv[4 + r], g1 ? d1[r] : FLT_MAX);
    }
  }

  // reduce over the 16 lanes of each quad (cols), then atomic-merge per row
  unsigned int* maxb = (unsigned int*)(ws + MAXB_OFF);
  unsigned int* minb = (unsigned int*)(ws + MINB_OFF);
#pragma unroll
  for (int r = 0; r < 8; ++r) {
    float mx = maxv[r], mn = minv[r];
#pragma unroll
    for (int sh = 1; sh <= 8; sh <<= 1) {
      mx = fmaxf(mx, __shfl_xor(mx, sh, 64));
      mn = fminf(mn, __shfl_xor(mn, sh, 64));
    }
    if (n == 0) {
      int row = i0 + (r < 4 ? 0 : 16) + quad * 4 + (r & 3);
      atomicMax(maxb + row, __float_as_uint(fmaxf(mx, 0.f)));
      atomicMin(minb + row, __float_as_uint(fmaxf(mn, 0.f)));
    }
  }
}

// ---------------------------------------------------------------------------
// Phase 3: final loss reduction (single block, float4 loads)
// ---------------------------------------------------------------------------
__global__ __launch_bounds__(256) void hcl_loss(const char* __restrict__ ws,
                                               float* __restrict__ out) {
  int t = threadIdx.x;
  const float4* maxb = (const float4*)(ws + MAXB_OFF);
  const float4* minb = (const float4*)(ws + MINB_OFF);
  float sp = 0.f, sn = 0.f;
#pragma unroll
  for (int k = 0; k < 8; ++k) {
    float4 mx = maxb[t + 256 * k];
    float4 mn = minb[t + 256 * k];
    sp += fmaxf(sqrtf(mx.x + EPSF) - POS_TH, 0.f) + fmaxf(sqrtf(mx.y + EPSF) - POS_TH, 0.f) +
          fmaxf(sqrtf(mx.z + EPSF) - POS_TH, 0.f) + fmaxf(sqrtf(mx.w + EPSF) - POS_TH, 0.f);
    sn += fmaxf(NEG_TH - sqrtf(mn.x + EPSF), 0.f) + fmaxf(NEG_TH - sqrtf(mn.y + EPSF), 0.f) +
          fmaxf(NEG_TH - sqrtf(mn.z + EPSF), 0.f) + fmaxf(NEG_TH - sqrtf(mn.w + EPSF), 0.f);
  }
  __shared__ float red[8];
#pragma unroll
  for (int s = 32; s >= 1; s >>= 1) {
    sp += __shfl_down(sp, s, 64);
    sn += __shfl_down(sn, s, 64);
  }
  int wid = t >> 6;
  if ((t & 63) == 0) {
    red[wid] = sp;
    red[4 + wid] = sn;
  }
  __syncthreads();
  if (t == 0) {
    float tsp = red[0] + red[1] + red[2] + red[3];
    float tsn = red[4] + red[5] + red[6] + red[7];
    out[0] = (tsp + tsn) * (1.0f / NN);
  }
}

// ---------------------------------------------------------------------------
extern "C" void kernel_launch(void* const* d_in, const int* in_sizes, int n_in,
                              void* d_out, int out_size, void* d_ws, size_t ws_size,
                              hipStream_t stream) {
  const float* src_pcd = (const float*)d_in[0];
  const float* tgt_pcd = (const float*)d_in[1];
  const float* src_feats = (const float*)d_in[2];
  const float* tgt_feats = (const float*)d_in[3];
  const int* corr = (const int*)d_in[4];
  const float* rot = (const float*)d_in[5];
  const float* trans = (const float*)d_in[6];
  float* out = (float*)d_out;
  char* ws = (char*)d_ws;

  hcl_prep<<<NN * 4 / 256, 256, 0, stream>>>(src_pcd, tgt_pcd, src_feats, tgt_feats, corr,
                                             rot, trans, ws);
  hcl_dist<<<dim3(32, 64), 256, 0, stream>>>(ws);
  hcl_loss<<<1, 256, 0, stream>>>(ws, out);
}

// Round 7
// 101.467 us; speedup vs baseline: 2.8370x; 2.8370x over previous
//
#include <hip/hip_runtime.h>
#include <math.h>
#include <float.h>

#define NN 8192

typedef __bf16 bf16x8 __attribute__((ext_vector_type(8)));
typedef float f32x4 __attribute__((ext_vector_type(4)));

constexpr float POS_R2 = 0.0375f * 0.0375f;
constexpr float NEG_R2 = 0.1f * 0.1f;
constexpr float EPSF = 1e-7f;
constexpr float PRC = POS_R2 - EPSF;  // pos:  d2p < PRC
constexpr float NRC = NEG_R2 - EPSF;  // neg:  d2p > NRC
constexpr float POS_TH = 0.1f;
constexpr float NEG_TH = 1.4f;

// ws byte offsets
#define FT_OFF 0                          // bf16 [NN][32] tgt feats
#define FS2_OFF (NN * 64)                 // bf16 [NN][32] -2 * src feats
#define PSX_OFF (2 * NN * 64)             // bf16 [NN][32] src pos ext (A side)
#define PTX_OFF (3 * NN * 64)             // bf16 [NN][32] tgt pos ext (B side)
#define FNS_OFF (4 * NN * 64)             // f32 [NN] src feat |.|^2 (rounded feats)
#define FNT_OFF (4 * NN * 64 + NN * 4)    // f32 [NN] tgt feat |.|^2
#define MAXB_OFF (4 * NN * 64 + 2 * NN * 4)
#define MINB_OFF (4 * NN * 64 + 3 * NN * 4)

// ---------------------------------------------------------------------------
// Phase 1: gather + transform + bf16 conversion + MFMA operand packing.
// 4 threads per correspondence: part p handles feat dims [8p, 8p+8);
// p==1 builds src position-ext row, p==2 builds tgt position-ext row.
// ---------------------------------------------------------------------------
__global__ __launch_bounds__(256) void hcl_prep(
    const float* __restrict__ src_pcd, const float* __restrict__ tgt_pcd,
    const float* __restrict__ src_feats, const float* __restrict__ tgt_feats,
    const int* __restrict__ corr, const float* __restrict__ rot,
    const float* __restrict__ trans, char* __restrict__ ws) {
  int t = blockIdx.x * 256 + threadIdx.x;  // 0..32767
  int i = t >> 2;
  int p = t & 3;
  int ci = corr[2 * i];
  int cj = corr[2 * i + 1];

  // ---- feats: this part's 8 dims = float4 chunks 2p, 2p+1 ----
  const float4* sf = (const float4*)(src_feats + (size_t)ci * 32);
  const float4* tf = (const float4*)(tgt_feats + (size_t)cj * 32);
  float na = 0.f, nb = 0.f;
  bf16x8 osrc, otgt;
#pragma unroll
  for (int h = 0; h < 2; ++h) {
    float4 a = sf[2 * p + h];
    __bf16 h0 = (__bf16)a.x, h1 = (__bf16)a.y, h2 = (__bf16)a.z, h3 = (__bf16)a.w;
    float f0 = (float)h0, f1 = (float)h1, f2 = (float)h2, f3 = (float)h3;
    na += f0 * f0 + f1 * f1 + f2 * f2 + f3 * f3;
    osrc[4 * h + 0] = (__bf16)(-2.f * f0);
    osrc[4 * h + 1] = (__bf16)(-2.f * f1);
    osrc[4 * h + 2] = (__bf16)(-2.f * f2);
    osrc[4 * h + 3] = (__bf16)(-2.f * f3);

    float4 b = tf[2 * p + h];
    __bf16 g0 = (__bf16)b.x, g1 = (__bf16)b.y, g2 = (__bf16)b.z, g3 = (__bf16)b.w;
    nb += (float)g0 * (float)g0 + (float)g1 * (float)g1 + (float)g2 * (float)g2 +
          (float)g3 * (float)g3;
    otgt[4 * h + 0] = g0;
    otgt[4 * h + 1] = g1;
    otgt[4 * h + 2] = g2;
    otgt[4 * h + 3] = g3;
  }
  *(bf16x8*)(ws + FS2_OFF + (size_t)i * 64 + p * 16) = osrc;
  *(bf16x8*)(ws + FT_OFF + (size_t)i * 64 + p * 16) = otgt;

  // reduce norms across the 4 parts (adjacent lanes)
  na += __shfl_xor(na, 1, 4);
  na += __shfl_xor(na, 2, 4);
  nb += __shfl_xor(nb, 1, 4);
  nb += __shfl_xor(nb, 2, 4);

  __bf16 one = (__bf16)1.0f, zero = (__bf16)0.0f;

  if (p == 0) {
    ((float*)(ws + FNS_OFF))[i] = na;
    ((float*)(ws + FNT_OFF))[i] = nb;
    ((unsigned int*)(ws + MAXB_OFF))[i] = 0u;           // max(d2f) sentinel
    ((unsigned int*)(ws + MINB_OFF))[i] = 0x7F7FFFFFu;  // FLT_MAX bits
  } else if (p == 1) {
    // src position-ext row: [ahi(3), ahi(3), alo(3), sahi, salo, 1, 1, 0...]
    float r00 = rot[0], r01 = rot[1], r02 = rot[2];
    float r10 = rot[3], r11 = rot[4], r12 = rot[5];
    float r20 = rot[6], r21 = rot[7], r22 = rot[8];
    float t0 = trans[0], t1 = trans[1], t2 = trans[2];
    float px = src_pcd[ci * 3 + 0], py = src_pcd[ci * 3 + 1], pz = src_pcd[ci * 3 + 2];
    float qx = r00 * px + r01 * py + r02 * pz + t0;
    float qy = r10 * px + r11 * py + r12 * pz + t1;
    float qz = r20 * px + r21 * py + r22 * pz + t2;
    float sa = qx * qx + qy * qy + qz * qz;
    __bf16 qhx = (__bf16)qx, qhy = (__bf16)qy, qhz = (__bf16)qz;
    __bf16 qlx = (__bf16)(qx - (float)qhx);
    __bf16 qly = (__bf16)(qy - (float)qhy);
    __bf16 qlz = (__bf16)(qz - (float)qhz);
    __bf16 sah = (__bf16)sa;
    __bf16 sal = (__bf16)(sa - (float)sah);
    bf16x8 v0, v1, vz;
    v0[0] = qhx; v0[1] = qhy; v0[2] = qhz; v0[3] = qhx; v0[4] = qhy; v0[5] = qhz;
    v0[6] = qlx; v0[7] = qly;
    v1[0] = qlz; v1[1] = sah; v1[2] = sal; v1[3] = one; v1[4] = one;
    v1[5] = zero; v1[6] = zero; v1[7] = zero;
#pragma unroll
    for (int k = 0; k < 8; ++k) vz[k] = zero;
    bf16x8* o = (bf16x8*)(ws + PSX_OFF + (size_t)i * 64);
    o[0] = v0; o[1] = v1; o[2] = vz; o[3] = vz;
  } else if (p == 2) {
    // tgt position-ext row: [-2bhi(3), -2blo(3), -2bhi(3), 1, 1, sbhi, sblo, 0...]
    float ux = tgt_pcd[cj * 3 + 0], uy = tgt_pcd[cj * 3 + 1], uz = tgt_pcd[cj * 3 + 2];
    float sb = ux * ux + uy * uy + uz * uz;
    __bf16 uhx = (__bf16)ux, uhy = (__bf16)uy, uhz = (__bf16)uz;
    __bf16 ulx = (__bf16)(ux - (float)uhx);
    __bf16 uly = (__bf16)(uy - (float)uhy);
    __bf16 ulz = (__bf16)(uz - (float)uhz);
    __bf16 sbh = (__bf16)sb;
    __bf16 sbl = (__bf16)(sb - (float)sbh);
    __bf16 m2hx = (__bf16)(-2.f * (float)uhx), m2hy = (__bf16)(-2.f * (float)uhy),
           m2hz = (__bf16)(-2.f * (float)uhz);
    __bf16 m2lx = (__bf16)(-2.f * (float)ulx), m2ly = (__bf16)(-2.f * (float)uly),
           m2lz = (__bf16)(-2.f * (float)ulz);
    bf16x8 w0, w1, wz;
    w0[0] = m2hx; w0[1] = m2hy; w0[2] = m2hz; w0[3] = m2lx; w0[4] = m2ly; w0[5] = m2lz;
    w0[6] = m2hx; w0[7] = m2hy;
    w1[0] = m2hz; w1[1] = one; w1[2] = one; w1[3] = sbh; w1[4] = sbl;
    w1[5] = zero; w1[6] = zero; w1[7] = zero;
#pragma unroll
    for (int k = 0; k < 8; ++k) wz[k] = zero;
    bf16x8* o = (bf16x8*)(ws + PTX_OFF + (size_t)i * 64);
    o[0] = w0; o[1] = w1; o[2] = wz; o[3] = wz;
  }
}

// ---------------------------------------------------------------------------
// Phase 2: MFMA pairwise distances + masked row max/min. No LDS, no barriers.
// EXACT Round-0 structure (best measured: dist ~40us, total 100.6us):
// wave = 32 rows (two 16x16 tiles) x 16-col steps; 8 outer x 4 unrolled inner
// col-groups, immediate-offset loads, one pointer bump per 4 groups.
// Grid = (16 j-chunks of 512, 64 row-blocks), 4 blocks/CU resident.
// ONLY change vs R0: skip bpos/apos loads for quads 2/3 -- ext-row elements
// 16..31 are structurally zero (verified correct in R4/R5/R6) -> -17% of
// inner-loop VMEM instructions, -25% of B-panel bytes, same registers.
// launch_bounds(256,4): VGPR 64, zero spill. (256,8) clamps to 32 and
// spills hundreds of MB to scratch (R2), full unroll also spills (R6).
// ---------------------------------------------------------------------------
__global__ __launch_bounds__(256, 4) void hcl_dist(char* __restrict__ ws) {
  const int lane = threadIdx.x & 63;
  const int wave = threadIdx.x >> 6;
  const int quad = lane >> 4;
  const int n = lane & 15;
  const int i0 = blockIdx.y * 128 + wave * 32;
  const int j0 = blockIdx.x * 512;
  const size_t aoff = (size_t)quad * 16;
  const bool ldp = quad < 2;  // pos-ext K=16..31 is structurally zero

  // A-side fragments (constant over the j loop)
  const bf16x8 afeat0 = *(const bf16x8*)(ws + FS2_OFF + (size_t)(i0 + n) * 64 + aoff);
  const bf16x8 afeat1 = *(const bf16x8*)(ws + FS2_OFF + (size_t)(i0 + 16 + n) * 64 + aoff);
  bf16x8 apos0, apos1;
  if (ldp) {
    apos0 = *(const bf16x8*)(ws + PSX_OFF + (size_t)(i0 + n) * 64 + aoff);
    apos1 = *(const bf16x8*)(ws + PSX_OFF + (size_t)(i0 + 16 + n) * 64 + aoff);
  } else {
#pragma unroll
    for (int k = 0; k < 8; ++k) { apos0[k] = (__bf16)0.0f; apos1[k] = (__bf16)0.0f; }
  }
  const f32x4 fa0 = *(const f32x4*)(ws + FNS_OFF + (size_t)(i0 + quad * 4) * 4);
  const f32x4 fa1 = *(const f32x4*)(ws + FNS_OFF + (size_t)(i0 + 16 + quad * 4) * 4);

  float maxv[8], minv[8];
#pragma unroll
  for (int r = 0; r < 8; ++r) {
    maxv[r] = -1.0f;
    minv[r] = FLT_MAX;
  }

  const char* pF = ws + FT_OFF + (size_t)(j0 + n) * 64 + aoff;
  const char* pP = ws + PTX_OFF + (size_t)(j0 + n) * 64 + aoff;
  const char* pN = ws + FNT_OFF + (size_t)(j0 + n) * 4;

  for (int s = 0; s < 8; ++s) {
#pragma unroll
    for (int u = 0; u < 4; ++u) {
      const bf16x8 bfeat = *(const bf16x8*)(pF + u * 1024);
      bf16x8 bpos;
#pragma unroll
      for (int k = 0; k < 8; ++k) bpos[k] = (__bf16)0.0f;
      if (ldp) bpos = *(const bf16x8*)(pP + u * 1024);
      const float fb = *(const float*)(pN + u * 64);

      f32x4 c0, c1, z;
      c0[0] = fa0[0] + fb; c0[1] = fa0[1] + fb; c0[2] = fa0[2] + fb; c0[3] = fa0[3] + fb;
      c1[0] = fa1[0] + fb; c1[1] = fa1[1] + fb; c1[2] = fa1[2] + fb; c1[3] = fa1[3] + fb;
      z[0] = 0.f; z[1] = 0.f; z[2] = 0.f; z[3] = 0.f;

      f32x4 d0 = __builtin_amdgcn_mfma_f32_16x16x32_bf16(afeat0, bfeat, c0, 0, 0, 0);
      f32x4 d1 = __builtin_amdgcn_mfma_f32_16x16x32_bf16(afeat1, bfeat, c1, 0, 0, 0);
      f32x4 u0 = __builtin_amdgcn_mfma_f32_16x16x32_bf16(apos0, bpos, z, 0, 0, 0);
      f32x4 u1 = __builtin_amdgcn_mfma_f32_16x16x32_bf16(apos1, bpos, z, 0, 0, 0);

#pragma unroll
      for (int r = 0; r < 4; ++r) {
        bool p0 = u0[r] < PRC, g0 = u0[r] > NRC;
        maxv[r] = fmaxf(maxv[r], p0 ? d0[r] : -1.0f);
        minv[r] = fminf(minv[r], g0 ? d0[r] : FLT_MAX);
        bool p1 = u1[r] < PRC, g1 = u1[r] > NRC;
        maxv[4 + r] = fmaxf(maxv[4 + r], p1 ? d1[r] : -1.0f);
        minv[4 + r] = fminf(minv[4 + r], g1 ? d1[r] : FLT_MAX);
      }
    }
    pF += 4096;
    pP += 4096;
    pN += 256;
  }

  // reduce over the 16 lanes of each quad (cols), then atomic-merge per row
  unsigned int* maxb = (unsigned int*)(ws + MAXB_OFF);
  unsigned int* minb = (unsigned int*)(ws + MINB_OFF);
#pragma unroll
  for (int r = 0; r < 8; ++r) {
    float mx = maxv[r], mn = minv[r];
#pragma unroll
    for (int sh = 1; sh <= 8; sh <<= 1) {
      mx = fmaxf(mx, __shfl_xor(mx, sh, 64));
      mn = fminf(mn, __shfl_xor(mn, sh, 64));
    }
    if (n == 0) {
      int row = i0 + (r < 4 ? 0 : 16) + quad * 4 + (r & 3);
      atomicMax(maxb + row, __float_as_uint(fmaxf(mx, 0.f)));
      atomicMin(minb + row, __float_as_uint(fmaxf(mn, 0.f)));
    }
  }
}

// ---------------------------------------------------------------------------
// Phase 3: final loss reduction (single block, float4 loads)
// ---------------------------------------------------------------------------
__global__ __launch_bounds__(256) void hcl_loss(const char* __restrict__ ws,
                                               float* __restrict__ out) {
  int t = threadIdx.x;
  const float4* maxb = (const float4*)(ws + MAXB_OFF);
  const float4* minb = (const float4*)(ws + MINB_OFF);
  float sp = 0.f, sn = 0.f;
#pragma unroll
  for (int k = 0; k < 8; ++k) {
    float4 mx = maxb[t + 256 * k];
    float4 mn = minb[t + 256 * k];
    sp += fmaxf(sqrtf(mx.x + EPSF) - POS_TH, 0.f) + fmaxf(sqrtf(mx.y + EPSF) - POS_TH, 0.f) +
          fmaxf(sqrtf(mx.z + EPSF) - POS_TH, 0.f) + fmaxf(sqrtf(mx.w + EPSF) - POS_TH, 0.f);
    sn += fmaxf(NEG_TH - sqrtf(mn.x + EPSF), 0.f) + fmaxf(NEG_TH - sqrtf(mn.y + EPSF), 0.f) +
          fmaxf(NEG_TH - sqrtf(mn.z + EPSF), 0.f) + fmaxf(NEG_TH - sqrtf(mn.w + EPSF), 0.f);
  }
  __shared__ float red[8];
#pragma unroll
  for (int s = 32; s >= 1; s >>= 1) {
    sp += __shfl_down(sp, s, 64);
    sn += __shfl_down(sn, s, 64);
  }
  int wid = t >> 6;
  if ((t & 63) == 0) {
    red[wid] = sp;
    red[4 + wid] = sn;
  }
  __syncthreads();
  if (t == 0) {
    float tsp = red[0] + red[1] + red[2] + red[3];
    float tsn = red[4] + red[5] + red[6] + red[7];
    out[0] = (tsp + tsn) * (1.0f / NN);
  }
}

// ---------------------------------------------------------------------------
extern "C" void kernel_launch(void* const* d_in, const int* in_sizes, int n_in,
                              void* d_out, int out_size, void* d_ws, size_t ws_size,
                              hipStream_t stream) {
  const float* src_pcd = (const float*)d_in[0];
  const float* tgt_pcd = (const float*)d_in[1];
  const float* src_feats = (const float*)d_in[2];
  const float* tgt_feats = (const float*)d_in[3];
  const int* corr = (const int*)d_in[4];
  const float* rot = (const float*)d_in[5];
  const float* trans = (const float*)d_in[6];
  float* out = (float*)d_out;
  char* ws = (char*)d_ws;

  hcl_prep<<<NN * 4 / 256, 256, 0, stream>>>(src_pcd, tgt_pcd, src_feats, tgt_feats, corr,
                                             rot, trans, ws);
  hcl_dist<<<dim3(16, 64), 256, 0, stream>>>(ws);
  hcl_loss<<<1, 256, 0, stream>>>(ws, out);
}